// Round 8
// baseline (7589.095 us; speedup 1.0000x reference)
//
#include <hip/hip_runtime.h>

// LTC RNN (LiquidNeuralNetwork): B=512, S=512, H=128, 2 layers, RK4.
// Round 8: wave-specialized pipeline. Rounds 1-7 showed per-step time pinned
// at ~9-10k cyc by phase-aligned lockstep (4 barriers/step, all waves stall
// together); issue-cost floor is ~4-5k cyc/step. New structure: 32 blocks x
// 256 threads = 4 waves, one per SIMD, each autonomous between barriers:
//   w0 = L0 full RK4 step (8 row-tiles, A0 weights in 256 VGPRs), step i-1
//   w1 = L1 full RK4 step (A1 in VGPRs), step i-3
//   w2 = x-proj server: U0(i) = (Win0 x, Wg0x x + bg0)  (AX in VGPRs)
//   w3 = io-proj server: U1(i-2) = (Win1 h0, Wg1x h0 + bg1) (AIO in VGPRs)
// RK stages chain through wave-PRIVATE LDS scratch (per-wave DS ops are
// in-order -> no barrier between stages). Handoffs (hq / U0 / U1 / xt) are
// f16 double-buffered in LDS; exactly ONE __syncthreads per marker
// (515 total vs 2052). waves_per_eu(1,1) + 256-thread block -> 512-VGPR
// budget so the weight-resident sets cannot be spilled by an occupancy
// heuristic (the r5-r7 failure mode).

typedef _Float16 f16;
typedef _Float16 f16x4 __attribute__((ext_vector_type(4)));
typedef _Float16 f16x8 __attribute__((ext_vector_type(8)));
typedef float f32x4 __attribute__((ext_vector_type(4)));

#define NSTEP 512
#define OFF_A0 0
#define OFF_A1 32768
#define OFF_AIO 65536
#define OFF_AX 98304
#define W_TOTAL 122880

// LDS byte map. [c][136] f16 buffers are 4352 B.
#define SC0 0        // w0 private stage scratch
#define SC1 4352     // w1 private stage scratch (also holds h1 state handoff to itself)
#define HQB 8704     // h0 handoff, dbuf: 8704 + s*4352
#define U0B 17408    // U0 dbuf: +s*8704 (u at +0, g at +2176 f16 elems)
#define U1B 34816    // U1 dbuf: +s*8704
#define XTB 52224    // x tile dbuf: +s*2304, [c][72] f16
#define LDS_TOTAL 56832

__device__ __forceinline__ float rcp_f(float x) { return __builtin_amdgcn_rcpf(x); }
__device__ __forceinline__ float tanh_f(float x) {
  float e = __expf(2.f * x);
  return 1.f - 2.f * rcp_f(e + 1.f);
}
// sigmoid(t), t in [-1,1]: odd Taylor of 0.5+0.5*tanh(t/2), |err|<3e-6
__device__ __forceinline__ float sig_poly(float t) {
  float s = t * t;
  float p = fmaf(s, 2.1356861e-5f, -2.1081349e-4f);
  p = fmaf(s, p, 2.0833333e-3f);
  p = fmaf(s, p, -2.0833333e-2f);
  p = fmaf(s, p, 0.25f);
  return fmaf(t, p, 0.5f);
}

// Weight prep: identical layout to rounds 1-7 (verified).
// A-frag (16x16x32): A[m=lane&15][k=(lane>>4)*8+j], row-tile T = rows 16T..16T+15.
// A0 @0      [T8][sel2][kc4][lane64][j8]  sel0=Wg0 h-part, sel1=Wrec0
// A1 @32768  same                          sel0=Wg1 h-part, sel1=Wrec1
// AIO@65536  same                          sel0=Win1,       sel1=Wg1 x-part
// AX @98304  [T8][sel2][kc3][lane64][j8]  sel0=Win0,       sel1=Wg0 x-part (K=96)
__global__ __launch_bounds__(256) void prep_kernel(
    const float* __restrict__ Win0, const float* __restrict__ Wrec0,
    const float* __restrict__ Wg0, const float* __restrict__ Win1,
    const float* __restrict__ Wrec1, const float* __restrict__ Wg1,
    f16* __restrict__ W) {
  int i = blockIdx.x * 256 + threadIdx.x;
  if (i >= W_TOTAL) return;
  if (i < OFF_AX) {
    int sec = i >> 15;
    int r = i & 32767;
    int j = r & 7, lane = (r >> 3) & 63, kc = (r >> 9) & 3, sel = (r >> 11) & 1,
        w = (r >> 12) & 7;
    int row = w * 16 + (lane & 15);
    int k = kc * 32 + ((lane >> 4) << 3) + j;
    float v;
    if (sec == 0)
      v = sel ? Wrec0[row * 128 + k] : Wg0[row * 224 + 96 + k];
    else if (sec == 1)
      v = sel ? Wrec1[row * 128 + k] : Wg1[row * 256 + 128 + k];
    else
      v = sel ? Wg1[row * 256 + k] : Win1[row * 128 + k];
    W[i] = (f16)v;
  } else {
    int r = i - OFF_AX;
    int j = r & 7, lane = (r >> 3) & 63, g = r >> 9;
    int kc = g % 3, sg = g / 3;
    int sel = sg & 1, w = sg >> 1;
    int row = w * 16 + (lane & 15);
    int k = kc * 32 + ((lane >> 4) << 3) + j;
    W[i] = (f16)(sel ? Wg0[row * 224 + k] : Win0[row * 96 + k]);
  }
}

#define MFMA16(A, B, C) __builtin_amdgcn_mfma_f32_16x16x32_f16((A), (B), (C), 0, 0, 0)
#define ZERO4 ((f32x4){0.f, 0.f, 0.f, 0.f})

// One RK stage for an L-wave: full 128x128 gate+rec matvec (64 MFMA),
// 32 gate evals, write eval point / new state to DSTP. B-frag from SRCP
// (wave-private or handoff buffer); ZB -> zeros (h(-1)=0).
#define LSTAGE(SRCP, DSTP, WC, HC, ISFIRST, ISFINAL, ZB)                      \
  {                                                                           \
    f16x8 bf0, bf1, bf2, bf3;                                                 \
    if (ZB) {                                                                 \
      bf0 = (f16x8)(f16)0.f; bf1 = bf0; bf2 = bf0; bf3 = bf0;                 \
    } else {                                                                  \
      const f16* bp_ = (SRCP) + c * 136 + 8 * q;                              \
      bf0 = *(const f16x8*)(bp_);                                             \
      bf1 = *(const f16x8*)(bp_ + 32);                                        \
      bf2 = *(const f16x8*)(bp_ + 64);                                        \
      bf3 = *(const f16x8*)(bp_ + 96);                                        \
    }                                                                         \
    _Pragma("unroll") for (int T = 0; T < 8; ++T) {                           \
      f32x4 ga = ZERO4, ra = ZERO4;                                           \
      ga = MFMA16(ag[T][0], bf0, ga); ra = MFMA16(ar[T][0], bf0, ra);         \
      ga = MFMA16(ag[T][1], bf1, ga); ra = MFMA16(ar[T][1], bf1, ra);         \
      ga = MFMA16(ag[T][2], bf2, ga); ra = MFMA16(ar[T][2], bf2, ra);         \
      ga = MFMA16(ag[T][3], bf3, ga); ra = MFMA16(ar[T][3], bf3, ra);         \
      f16x4 uu = *(const f16x4*)(ubuf + c * 136 + 16 * T + 4 * q);            \
      f16x4 gg = *(const f16x4*)(ubuf + 2176 + c * 136 + 16 * T + 4 * q);     \
      f16x4 hv;                                                               \
      _Pragma("unroll") for (int r = 0; r < 4; ++r) {                         \
        float th_ = tanh_f(ga[r] + (float)gg[r]);                             \
        float gt_ = sig_poly(th_);                                            \
        float kk_ = fmaf(gt_, ra[r],                                          \
                         fmaf(-pv[T][r], hhc[T][r], (float)uu[r]));           \
        ksum[T][r] = (ISFIRST) ? kk_ : fmaf((WC), kk_, ksum[T][r]);           \
        float hn_;                                                            \
        if (ISFINAL) {                                                        \
          hn_ = tanh_f(fmaf(ksum[T][r], 0.16666667f, hst[T][r]));             \
          hst[T][r] = hn_;                                                    \
        } else {                                                              \
          hn_ = fmaf((HC), kk_, hst[T][r]);                                   \
        }                                                                     \
        hhc[T][r] = hn_;                                                      \
        hv[r] = (f16)hn_;                                                     \
      }                                                                       \
      *(f16x4*)((DSTP) + c * 136 + 16 * T + 4 * q) = hv;                      \
    }                                                                         \
  }

__global__ __attribute__((amdgpu_flat_work_group_size(256, 256)))
__attribute__((amdgpu_waves_per_eu(1, 1))) void ltc_kernel(
    const float* __restrict__ seq, const float* __restrict__ ctx,
    const float* __restrict__ tau0p, const float* __restrict__ bg0p,
    const float* __restrict__ tau1p, const float* __restrict__ bg1p,
    const float* __restrict__ W1, const float* __restrict__ b1,
    const float* __restrict__ W2, const float* __restrict__ b2,
    const f16* __restrict__ W, float* __restrict__ out) {
  __shared__ __align__(16) char smem[LDS_TOTAL];

  const int tid = threadIdx.x;
  const int w = tid >> 6, lane = tid & 63;
  const int q = lane >> 4, c = lane & 15;
  const int bg = blockIdx.x;

  f16* sc = (f16*)(smem + (w == 0 ? SC0 : SC1));  // private scratch (w0/w1)

  // ---- weight fragments -> VGPRs, role-dependent ----
  // w0: ag=Wg0h, ar=Wrec0. w1: ag=Wg1h, ar=Wrec1.
  // w2: ag=Win0, ar=Wg0x (3 kc). w3: ag=Win1, ar=Wg1x.
  f16x8 ag[8][4], ar[8][4];
  if (w == 2) {
#pragma unroll
    for (int T = 0; T < 8; ++T) {
#pragma unroll
      for (int kc = 0; kc < 3; ++kc) {
        ag[T][kc] = *(const f16x8*)(W + OFF_AX + (((T * 2 + 0) * 3 + kc) * 64 + lane) * 8);
        ar[T][kc] = *(const f16x8*)(W + OFF_AX + (((T * 2 + 1) * 3 + kc) * 64 + lane) * 8);
      }
      ag[T][3] = (f16x8)(f16)0.f;
      ar[T][3] = (f16x8)(f16)0.f;
    }
  } else {
    const int offA = (w == 0) ? OFF_A0 : (w == 1) ? OFF_A1 : OFF_AIO;
#pragma unroll
    for (int T = 0; T < 8; ++T) {
#pragma unroll
      for (int kc = 0; kc < 4; ++kc) {
        ag[T][kc] = *(const f16x8*)(W + offA + (((T * 2 + 0) * 4 + kc) * 64 + lane) * 8);
        ar[T][kc] = *(const f16x8*)(W + offA + (((T * 2 + 1) * 4 + kc) * 64 + lane) * 8);
      }
    }
  }

  // per-lane row params: w0/w1 -> 1/(softplus(tau)+1); w2/w3 -> gate bias
  const float* pp = (w == 0) ? tau0p : (w == 1) ? tau1p : (w == 2) ? bg0p : bg1p;
  f32x4 pv[8];
#pragma unroll
  for (int T = 0; T < 8; ++T) {
    f32x4 t4 = *(const f32x4*)(pp + 16 * T + 4 * q);
    if (w < 2) {
#pragma unroll
      for (int r = 0; r < 4; ++r)
        pv[T][r] = 1.f / (logf(1.f + __expf(t4[r])) + 1.f);
    } else {
      pv[T] = t4;
    }
  }

  // ctx B-frag (w2 only, t-invariant)
  f16x8 bctx = (f16x8)(f16)0.f;
  if (w == 2) {
    const float* cp = ctx + (bg * 16 + c) * 32 + 8 * q;
#pragma unroll
    for (int j = 0; j < 8; ++j) bctx[j] = (f16)cp[j];
    // pre-stage x(0) into XT[0]
    int col = lane >> 2, fb = lane & 3;
    const float* gp = seq + ((size_t)(bg * 16 + col) * NSTEP + 0) * 64 + fb * 16;
    float4 v0 = *(const float4*)(gp);
    float4 v1 = *(const float4*)(gp + 4);
    float4 v2 = *(const float4*)(gp + 8);
    float4 v3 = *(const float4*)(gp + 12);
    f16x8 ha, hb;
    ha[0] = (f16)v0.x; ha[1] = (f16)v0.y; ha[2] = (f16)v0.z; ha[3] = (f16)v0.w;
    ha[4] = (f16)v1.x; ha[5] = (f16)v1.y; ha[6] = (f16)v1.z; ha[7] = (f16)v1.w;
    hb[0] = (f16)v2.x; hb[1] = (f16)v2.y; hb[2] = (f16)v2.z; hb[3] = (f16)v2.w;
    hb[4] = (f16)v3.x; hb[5] = (f16)v3.y; hb[6] = (f16)v3.z; hb[7] = (f16)v3.w;
    f16* xd = (f16*)(smem + XTB) + col * 72 + fb * 16;
    *(f16x8*)(xd) = ha;
    *(f16x8*)(xd + 8) = hb;
  }

  // L-wave state (w0/w1)
  f32x4 hst[8], ksum[8], hhc[8];
#pragma unroll
  for (int T = 0; T < 8; ++T) { hst[T] = ZERO4; ksum[T] = ZERO4; hhc[T] = ZERO4; }

  __syncthreads();  // x(0) staged; weights loaded

  // ===== marker loop: i = 0 .. NSTEP+2 (one barrier per marker) =====
#pragma unroll 1
  for (int i = 0; i <= NSTEP + 2; ++i) {
    if (w < 2) {
      // w0 processes L0 step j=i-1; w1 processes L1 step j=i-3
      const int j = i - 1 - 2 * w;
      if (j >= 0 && j < NSTEP) {
        const f16* ubuf =
            (const f16*)(smem + (w == 0 ? U0B : U1B) + (j & 1) * 8704);
        const f16* s1 = (w == 0)
                            ? (const f16*)(smem + HQB + ((j - 1) & 1) * 4352)
                            : sc;  // w1: own scratch holds h1(j-1)
        f16* s4 = (w == 0) ? (f16*)(smem + HQB + (j & 1) * 4352) : sc;
        const bool zb = (j == 0);
        LSTAGE(s1, sc, 1.0f, 0.5f, true, false, zb);
        LSTAGE(sc, sc, 2.0f, 0.5f, false, false, false);
        LSTAGE(sc, sc, 2.0f, 1.0f, false, false, false);
        LSTAGE(sc, s4, 1.0f, 0.0f, false, true, false);
      }
    } else if (w == 2) {
      // x-proj: U0(i) from XT[i&1]; then stage x(i+1) into XT[(i+1)&1]
      if (i < NSTEP) {
        const f16* xb = (const f16*)(smem + XTB + (i & 1) * 2304);
        f16x8 bx0 = *(const f16x8*)(xb + c * 72 + 8 * q);
        f16x8 bx1 = *(const f16x8*)(xb + c * 72 + 32 + 8 * q);
        f16* du = (f16*)(smem + U0B + (i & 1) * 8704);
#pragma unroll
        for (int T = 0; T < 8; ++T) {
          f32x4 au = ZERO4, agx = ZERO4;
          au = MFMA16(ag[T][0], bx0, au); agx = MFMA16(ar[T][0], bx0, agx);
          au = MFMA16(ag[T][1], bx1, au); agx = MFMA16(ar[T][1], bx1, agx);
          au = MFMA16(ag[T][2], bctx, au); agx = MFMA16(ar[T][2], bctx, agx);
          f16x4 hu, hg;
#pragma unroll
          for (int r = 0; r < 4; ++r) {
            hu[r] = (f16)au[r];
            hg[r] = (f16)(agx[r] + pv[T][r]);  // fold bg0 here
          }
          *(f16x4*)(du + c * 136 + 16 * T + 4 * q) = hu;
          *(f16x4*)(du + 2176 + c * 136 + 16 * T + 4 * q) = hg;
        }
        if (i + 1 < NSTEP) {
          int col = lane >> 2, fb = lane & 3;
          const float* gp =
              seq + ((size_t)(bg * 16 + col) * NSTEP + (i + 1)) * 64 + fb * 16;
          float4 v0 = *(const float4*)(gp);
          float4 v1 = *(const float4*)(gp + 4);
          float4 v2 = *(const float4*)(gp + 8);
          float4 v3 = *(const float4*)(gp + 12);
          f16x8 ha, hb;
          ha[0] = (f16)v0.x; ha[1] = (f16)v0.y; ha[2] = (f16)v0.z; ha[3] = (f16)v0.w;
          ha[4] = (f16)v1.x; ha[5] = (f16)v1.y; ha[6] = (f16)v1.z; ha[7] = (f16)v1.w;
          hb[0] = (f16)v2.x; hb[1] = (f16)v2.y; hb[2] = (f16)v2.z; hb[3] = (f16)v2.w;
          hb[4] = (f16)v3.x; hb[5] = (f16)v3.y; hb[6] = (f16)v3.z; hb[7] = (f16)v3.w;
          f16* xd = (f16*)(smem + XTB + ((i + 1) & 1) * 2304) + col * 72 + fb * 16;
          *(f16x8*)(xd) = ha;
          *(f16x8*)(xd + 8) = hb;
        }
      }
    } else {
      // w3: io-proj U1(t2) from HQ[t2&1], t2 = i-2
      const int t2 = i - 2;
      if (t2 >= 0 && t2 < NSTEP) {
        const f16* bp = (const f16*)(smem + HQB + (t2 & 1) * 4352) + c * 136 + 8 * q;
        f16x8 b0 = *(const f16x8*)(bp);
        f16x8 b1 = *(const f16x8*)(bp + 32);
        f16x8 b2v = *(const f16x8*)(bp + 64);
        f16x8 b3 = *(const f16x8*)(bp + 96);
        f16* du = (f16*)(smem + U1B + (t2 & 1) * 8704);
#pragma unroll
        for (int T = 0; T < 8; ++T) {
          f32x4 au = ZERO4, agx = ZERO4;
          au = MFMA16(ag[T][0], b0, au); agx = MFMA16(ar[T][0], b0, agx);
          au = MFMA16(ag[T][1], b1, au); agx = MFMA16(ar[T][1], b1, agx);
          au = MFMA16(ag[T][2], b2v, au); agx = MFMA16(ar[T][2], b2v, agx);
          au = MFMA16(ag[T][3], b3, au); agx = MFMA16(ar[T][3], b3, agx);
          f16x4 hu, hg;
#pragma unroll
          for (int r = 0; r < 4; ++r) {
            hu[r] = (f16)au[r];
            hg[r] = (f16)(agx[r] + pv[T][r]);  // fold bg1 here
          }
          *(f16x4*)(du + c * 136 + 16 * T + 4 * q) = hu;
          *(f16x4*)(du + 2176 + c * 136 + 16 * T + 4 * q) = hg;
        }
      }
    }
    __syncthreads();
  }

  // ======================= classifier epilogue ===========================
  float* h1f = (float*)smem;  // [16][132] f32 (SC0/SC1 dead)
  if (w == 1) {
#pragma unroll
    for (int T = 0; T < 8; ++T)
      *(f32x4*)(h1f + c * 132 + 16 * T + 4 * q) = hst[T];
  }
  __syncthreads();
  float* z1 = (float*)(smem + 8704);  // [16][64] f32 (HQ dead)
#pragma unroll
  for (int kk2 = 0; kk2 < 4; ++kk2) {
    int item = tid + 256 * kk2;
    int b = item >> 6, o = item & 63;
    const float* wr = W1 + o * 128;
    const float* hr = h1f + b * 132;
    float s = 0.f;
#pragma unroll
    for (int jj = 0; jj < 128; jj += 4) {
      f32x4 wv = *(const f32x4*)(wr + jj);
      f32x4 hv = *(const f32x4*)(hr + jj);
      s += wv[0] * hv[0] + wv[1] * hv[1] + wv[2] * hv[2] + wv[3] * hv[3];
    }
    s += b1[o];
    z1[b * 64 + o] = fmaxf(s, 0.f);
  }
  __syncthreads();
  if (tid < 16) {
    float s = b2[0];
#pragma unroll
    for (int o = 0; o < 64; ++o) s += z1[tid * 64 + o] * W2[o];
    out[bg * 16 + tid] = rcp_f(1.f + __expf(-s));
  }
}

extern "C" void kernel_launch(void* const* d_in, const int* in_sizes, int n_in,
                              void* d_out, int out_size, void* d_ws, size_t ws_size,
                              hipStream_t stream) {
  (void)in_sizes; (void)n_in; (void)out_size; (void)ws_size;
  const float* seq = (const float*)d_in[0];
  const float* ctx = (const float*)d_in[1];
  const float* tau0 = (const float*)d_in[2];
  const float* Win0 = (const float*)d_in[3];
  const float* Wrec0 = (const float*)d_in[4];
  const float* Wg0 = (const float*)d_in[5];
  const float* bg0 = (const float*)d_in[6];
  const float* tau1 = (const float*)d_in[7];
  const float* Win1 = (const float*)d_in[8];
  const float* Wrec1 = (const float*)d_in[9];
  const float* Wg1 = (const float*)d_in[10];
  const float* bg1 = (const float*)d_in[11];
  const float* W1 = (const float*)d_in[12];
  const float* b1 = (const float*)d_in[13];
  const float* W2 = (const float*)d_in[14];
  const float* b2 = (const float*)d_in[15];
  f16* W = (f16*)d_ws;  // 245760 B of packed fragments

  prep_kernel<<<480, 256, 0, stream>>>(Win0, Wrec0, Wg0, Win1, Wrec1, Wg1, W);
  ltc_kernel<<<32, 256, 0, stream>>>(seq, ctx, tau0, bg0, tau1, bg1, W1, b1, W2,
                                     b2, W, (float*)d_out);
}